// Round 2
// baseline (43.519 us; speedup 1.0000x reference)
//
#include <hip/hip_runtime.h>
#include <hip/hip_cooperative_groups.h>

namespace cg = cooperative_groups;

// CenterLoss: loss = mean_i clamp(||x_i - c_{l_i}||^2, 1e-12, 1e12) + (C_OUT-1)*1e-12
// (masked-then-clamped zeros contribute exactly (c_out-1)*1e-12 overall after /bs)

#define BS_N 8192
#define C_OUT_N 50000
#define D_N 64

#define NBLOCKS 256   // 1 block/CU -> trivially co-resident for cooperative launch
#define NTHREADS 256  // 4 waves/block

__global__ void center_loss_fused(const float* __restrict__ x,
                                  const int* __restrict__ labels,
                                  const float* __restrict__ centers,
                                  float* __restrict__ partials,
                                  float* __restrict__ out) {
    const int tid  = threadIdx.x;
    const int gtid = blockIdx.x * NTHREADS + tid;
    const int sub  = tid & 15;                        // 16 threads/row, float4 each
    const int row_stride = (NBLOCKS * NTHREADS) / 16; // 4096 rows per sweep

    float acc = 0.0f;
    for (int row = gtid >> 4; row < BS_N; row += row_stride) {
        const int lbl = labels[row];
        const float4 xv = *(const float4*)(x + row * D_N + sub * 4);
        const float4 cv = *(const float4*)(centers + lbl * D_N + sub * 4);
        const float dx = xv.x - cv.x;
        const float dy = xv.y - cv.y;
        const float dz = xv.z - cv.z;
        const float dw = xv.w - cv.w;
        float v = dx * dx + dy * dy + dz * dz + dw * dw;
        // reduce across the 16 lanes of this row-group (butterfly)
        v += __shfl_xor(v, 8, 64);
        v += __shfl_xor(v, 4, 64);
        v += __shfl_xor(v, 2, 64);
        v += __shfl_xor(v, 1, 64);
        if (sub == 0) acc += fminf(fmaxf(v, 1e-12f), 1e12f);
    }

    // wave reduction (lanes with sub!=0 carry 0)
    #pragma unroll
    for (int off = 32; off > 0; off >>= 1)
        acc += __shfl_down(acc, off, 64);

    __shared__ float smem[NTHREADS / 64];
    if ((tid & 63) == 0) smem[tid >> 6] = acc;
    __syncthreads();
    if (tid == 0) {
        const float s = smem[0] + smem[1] + smem[2] + smem[3];
        // agent-scope release so block 0 (possibly another XCD) sees it post-sync
        __hip_atomic_store(&partials[blockIdx.x], s,
                           __ATOMIC_RELEASE, __HIP_MEMORY_SCOPE_AGENT);
    }

    cg::this_grid().sync();

    if (blockIdx.x == 0) {
        float v = (tid < NBLOCKS)
                ? __hip_atomic_load(&partials[tid],
                                    __ATOMIC_ACQUIRE, __HIP_MEMORY_SCOPE_AGENT)
                : 0.0f;
        #pragma unroll
        for (int off = 32; off > 0; off >>= 1)
            v += __shfl_down(v, off, 64);
        __shared__ float smem2[NTHREADS / 64];
        if ((tid & 63) == 0) smem2[tid >> 6] = v;
        __syncthreads();
        if (tid == 0) {
            const float s = smem2[0] + smem2[1] + smem2[2] + smem2[3];
            const double loss = (double)s / (double)BS_N
                              + (double)(C_OUT_N - 1) * 1e-12;
            out[0] = (float)loss;
        }
    }
}

extern "C" void kernel_launch(void* const* d_in, const int* in_sizes, int n_in,
                              void* d_out, int out_size, void* d_ws, size_t ws_size,
                              hipStream_t stream) {
    const float* x        = (const float*)d_in[0];
    const int*   labels   = (const int*)d_in[1];
    const float* centers  = (const float*)d_in[2];
    float*       out      = (float*)d_out;
    float*       partials = (float*)d_ws;  // NBLOCKS floats

    void* args[] = {(void*)&x, (void*)&labels, (void*)&centers,
                    (void*)&partials, (void*)&out};
    hipLaunchCooperativeKernel((void*)center_loss_fused,
                               dim3(NBLOCKS), dim3(NTHREADS),
                               args, 0, stream);
}

// Round 3
// 15.412 us; speedup vs baseline: 2.8237x; 2.8237x over previous
//
#include <hip/hip_runtime.h>

// CenterLoss: loss = mean_i clamp(||x_i - c_{l_i}||^2, 1e-12, 1e12) + (C_OUT-1)*1e-12
// Single-dispatch design: 512 blocks each write (partial, ~bits(partial)) with
// release/agent scope; block 0 spin-validates all pairs then reduces in a FIXED
// order -> bitwise deterministic across graph replays. Poison (0xAAAAAAAA) and
// zeros both fail the chk==~val test, so no workspace reset is needed.

#define BS_N 8192
#define C_OUT_N 50000
#define D_N 64

#define NBLOCKS 512
#define NTHREADS 256
// 512 blocks * 256 threads / 16 threads-per-row = 8192 rows, single pass.

__global__ void center_loss_onepass(const float* __restrict__ x,
                                    const int* __restrict__ labels,
                                    const float* __restrict__ centers,
                                    unsigned* __restrict__ val_u,   // [NBLOCKS]
                                    unsigned* __restrict__ chk_u,   // [NBLOCKS]
                                    float* __restrict__ out) {
    const int tid = threadIdx.x;
    const int gid = blockIdx.x * NTHREADS + tid;
    const int sub = tid & 15;          // 16 threads/row, float4 each
    const int row = gid >> 4;

    const int lbl = labels[row];
    const float4 xv = *(const float4*)(x + row * D_N + sub * 4);
    const float4 cv = *(const float4*)(centers + (long)lbl * D_N + sub * 4);
    const float dx = xv.x - cv.x;
    const float dy = xv.y - cv.y;
    const float dz = xv.z - cv.z;
    const float dw = xv.w - cv.w;
    float v = dx * dx + dy * dy + dz * dz + dw * dw;
    // reduce across the 16 lanes of this row-group
    v += __shfl_xor(v, 8, 64);
    v += __shfl_xor(v, 4, 64);
    v += __shfl_xor(v, 2, 64);
    v += __shfl_xor(v, 1, 64);
    // clamp per-row, then sum the 4 row-leaders (lanes 0,16,32,48) of this wave
    float w = (sub == 0) ? fminf(fmaxf(v, 1e-12f), 1e12f) : 0.0f;
    w += __shfl_down(w, 32, 64);
    w += __shfl_down(w, 16, 64);

    __shared__ float smem[NTHREADS / 64];
    if ((tid & 63) == 0) smem[tid >> 6] = w;
    __syncthreads();
    if (tid == 0) {
        const float p = smem[0] + smem[1] + smem[2] + smem[3];
        const unsigned pb = __float_as_uint(p);
        __hip_atomic_store(&val_u[blockIdx.x], pb,
                           __ATOMIC_RELAXED, __HIP_MEMORY_SCOPE_AGENT);
        __hip_atomic_store(&chk_u[blockIdx.x], ~pb,
                           __ATOMIC_RELEASE, __HIP_MEMORY_SCOPE_AGENT);
    }

    // block 0, first wave: spin-validate all partials, reduce in fixed order
    if (blockIdx.x == 0 && tid < 64) {
        float s = 0.0f;
        #pragma unroll
        for (int k = 0; k < NBLOCKS / 64; ++k) {
            const int slot = tid + 64 * k;
            unsigned vbits;
            while (true) {
                const unsigned c = __hip_atomic_load(&chk_u[slot],
                                       __ATOMIC_ACQUIRE, __HIP_MEMORY_SCOPE_AGENT);
                vbits = __hip_atomic_load(&val_u[slot],
                                       __ATOMIC_RELAXED, __HIP_MEMORY_SCOPE_AGENT);
                if (c == ~vbits) break;
            }
            s += __uint_as_float(vbits);
        }
        #pragma unroll
        for (int off = 32; off > 0; off >>= 1)
            s += __shfl_down(s, off, 64);
        if (tid == 0) {
            const double loss = (double)s / (double)BS_N
                              + (double)(C_OUT_N - 1) * 1e-12;
            out[0] = (float)loss;
        }
    }
}

extern "C" void kernel_launch(void* const* d_in, const int* in_sizes, int n_in,
                              void* d_out, int out_size, void* d_ws, size_t ws_size,
                              hipStream_t stream) {
    const float* x       = (const float*)d_in[0];
    const int*   labels  = (const int*)d_in[1];
    const float* centers = (const float*)d_in[2];
    float*       out     = (float*)d_out;
    unsigned*    val_u   = (unsigned*)d_ws;            // NBLOCKS words
    unsigned*    chk_u   = val_u + NBLOCKS;            // NBLOCKS words

    center_loss_onepass<<<NBLOCKS, NTHREADS, 0, stream>>>(
        x, labels, centers, val_u, chk_u, out);
}

// Round 4
// 11.238 us; speedup vs baseline: 3.8724x; 1.3714x over previous
//
#include <hip/hip_runtime.h>

// CenterLoss: loss = mean_i clamp(||x_i - c_{l_i}||^2, 1e-12, 1e12) + (C_OUT-1)*1e-12
// Two-dispatch structure (graph edge = grid barrier). K1: 512 blocks, single
// pass, one 16-lane group per row. K2: one wave, float4-reduces 512 partials.

#define BS_N 8192
#define C_OUT_N 50000
#define D_N 64

#define NBLOCKS 512
#define NTHREADS 256
// 512 blocks * 256 threads / 16 threads-per-row = 8192 rows, single pass.

__global__ void center_loss_partial(const float* __restrict__ x,
                                    const int* __restrict__ labels,
                                    const float* __restrict__ centers,
                                    float* __restrict__ partials) {
    const int tid = threadIdx.x;
    const int gid = blockIdx.x * NTHREADS + tid;
    const int sub = tid & 15;          // 16 threads/row, float4 each
    const int row = gid >> 4;

    const int lbl = labels[row];
    const float4 xv = *(const float4*)(x + row * D_N + sub * 4);
    const float4 cv = *(const float4*)(centers + (long)lbl * D_N + sub * 4);
    const float dx = xv.x - cv.x;
    const float dy = xv.y - cv.y;
    const float dz = xv.z - cv.z;
    const float dw = xv.w - cv.w;
    float v = dx * dx + dy * dy + dz * dz + dw * dw;
    // reduce across the 16 lanes of this row-group
    v += __shfl_xor(v, 8, 64);
    v += __shfl_xor(v, 4, 64);
    v += __shfl_xor(v, 2, 64);
    v += __shfl_xor(v, 1, 64);
    // clamp per-row, then sum the 4 row-leaders (lanes 0,16,32,48) of this wave
    float w = (sub == 0) ? fminf(fmaxf(v, 1e-12f), 1e12f) : 0.0f;
    w += __shfl_down(w, 32, 64);
    w += __shfl_down(w, 16, 64);

    __shared__ float smem[NTHREADS / 64];
    if ((tid & 63) == 0) smem[tid >> 6] = w;
    __syncthreads();
    if (tid == 0)
        partials[blockIdx.x] = smem[0] + smem[1] + smem[2] + smem[3];
}

__global__ void center_loss_final(const float* __restrict__ partials,
                                  float* __restrict__ out) {
    const int lane = threadIdx.x;      // 64 threads = 1 wave
    const float4 a = *(const float4*)(partials + lane * 4);
    const float4 b = *(const float4*)(partials + 256 + lane * 4);
    float s = (a.x + a.y) + (a.z + a.w) + (b.x + b.y) + (b.z + b.w);
    #pragma unroll
    for (int off = 32; off > 0; off >>= 1)
        s += __shfl_down(s, off, 64);
    if (lane == 0) {
        const double loss = (double)s / (double)BS_N
                          + (double)(C_OUT_N - 1) * 1e-12;
        out[0] = (float)loss;
    }
}

extern "C" void kernel_launch(void* const* d_in, const int* in_sizes, int n_in,
                              void* d_out, int out_size, void* d_ws, size_t ws_size,
                              hipStream_t stream) {
    const float* x        = (const float*)d_in[0];
    const int*   labels   = (const int*)d_in[1];
    const float* centers  = (const float*)d_in[2];
    float*       out      = (float*)d_out;
    float*       partials = (float*)d_ws;  // NBLOCKS floats

    center_loss_partial<<<NBLOCKS, NTHREADS, 0, stream>>>(x, labels, centers, partials);
    center_loss_final<<<1, 64, 0, stream>>>(partials, out);
}

// Round 5
// 11.191 us; speedup vs baseline: 3.8887x; 1.0042x over previous
//
#include <hip/hip_runtime.h>

// CenterLoss: loss = mean_i clamp(||x_i - c_{l_i}||^2, 1e-12, 1e12) + (C_OUT-1)*1e-12
// Two-dispatch structure. K1: 512 blocks, one 16-lane group per row, each WAVE
// writes its own partial (no LDS, no __syncthreads -> waves retire independently).
// K2: one wave reduces 2048 partials in fixed order (bitwise deterministic).

#define BS_N 8192
#define C_OUT_N 50000
#define D_N 64

#define NBLOCKS 512
#define NTHREADS 256
#define NPART (NBLOCKS * NTHREADS / 64)   // 2048 per-wave partials

__global__ void center_loss_partial(const float* __restrict__ x,
                                    const int* __restrict__ labels,
                                    const float* __restrict__ centers,
                                    float* __restrict__ partials) {
    const int tid = threadIdx.x;
    const int gid = blockIdx.x * NTHREADS + tid;
    const int sub = tid & 15;          // 16 threads/row, float4 each
    const int row = gid >> 4;

    const int lbl = labels[row];
    const float4 xv = *(const float4*)(x + row * D_N + sub * 4);
    const float4 cv = *(const float4*)(centers + (long)lbl * D_N + sub * 4);
    const float dx = xv.x - cv.x;
    const float dy = xv.y - cv.y;
    const float dz = xv.z - cv.z;
    const float dw = xv.w - cv.w;
    float v = dx * dx + dy * dy + dz * dz + dw * dw;
    // reduce across the 16 lanes of this row-group
    v += __shfl_xor(v, 8, 64);
    v += __shfl_xor(v, 4, 64);
    v += __shfl_xor(v, 2, 64);
    v += __shfl_xor(v, 1, 64);
    // clamp per-row, then sum the 4 row-leaders (lanes 0,16,32,48) of this wave
    float w = (sub == 0) ? fminf(fmaxf(v, 1e-12f), 1e12f) : 0.0f;
    w += __shfl_down(w, 32, 64);
    w += __shfl_down(w, 16, 64);

    if ((tid & 63) == 0)
        partials[gid >> 6] = w;        // per-wave partial, no barrier needed
}

__global__ void center_loss_final(const float* __restrict__ partials,
                                  float* __restrict__ out) {
    const int lane = threadIdx.x;      // 64 threads = 1 wave
    float s = 0.0f;
    #pragma unroll
    for (int k = 0; k < NPART / 256; ++k) {   // 8 independent float4 loads
        const float4 a = *(const float4*)(partials + k * 256 + lane * 4);
        s += (a.x + a.y) + (a.z + a.w);
    }
    #pragma unroll
    for (int off = 32; off > 0; off >>= 1)
        s += __shfl_down(s, off, 64);
    if (lane == 0) {
        const double loss = (double)s / (double)BS_N
                          + (double)(C_OUT_N - 1) * 1e-12;
        out[0] = (float)loss;
    }
}

extern "C" void kernel_launch(void* const* d_in, const int* in_sizes, int n_in,
                              void* d_out, int out_size, void* d_ws, size_t ws_size,
                              hipStream_t stream) {
    const float* x        = (const float*)d_in[0];
    const int*   labels   = (const int*)d_in[1];
    const float* centers  = (const float*)d_in[2];
    float*       out      = (float*)d_out;
    float*       partials = (float*)d_ws;  // NPART floats

    center_loss_partial<<<NBLOCKS, NTHREADS, 0, stream>>>(x, labels, centers, partials);
    center_loss_final<<<1, 64, 0, stream>>>(partials, out);
}